// Round 5
// baseline (218.943 us; speedup 1.0000x reference)
//
#include <hip/hip_runtime.h>
#include <math.h>

#define NEG 0.2f
#define LNEPS 1e-5f

typedef __attribute__((ext_vector_type(8))) short bf16x8;
typedef __attribute__((ext_vector_type(4))) float f32x4;

__device__ __forceinline__ float lrelu(float x){ return x > 0.f ? x : NEG*x; }

// f32 -> bf16 (round to nearest even), as raw short
__device__ __forceinline__ short f2b(float f){
  unsigned u = __float_as_uint(f);
  unsigned r = u + 0x7fffu + ((u >> 16) & 1u);
  return (short)(r >> 16);
}
__device__ __forceinline__ float b2f(unsigned short u){
  return __uint_as_float(((unsigned)u) << 16);
}

// -------- W transpose + bf16 convert: WT[c][k] = bf16(W[k][c]) --------
__global__ __launch_bounds__(256) void wt_k(const float* __restrict__ W,
                                            unsigned short* __restrict__ WT){
  int idx = blockIdx.x*256 + threadIdx.x;   // 65536 elements
  int k = idx >> 8, c = idx & 255;
  WT[c*256 + k] = (unsigned short)f2b(W[idx]);
}

// -------- MFMA GEMM + fused att half-logits, B-in-registers --------
__device__ __forceinline__ void load_half(float4 nx[8], const float* p){
  #pragma unroll
  for (int s=0;s<4;s++){
    nx[2*s]   = *(const float4*)(p + s*32);
    nx[2*s+1] = *(const float4*)(p + s*32 + 4);
  }
}
__device__ __forceinline__ void cvt_half(bf16x8 af[4], const float4 nx[8]){
  #pragma unroll
  for (int s=0;s<4;s++){
    af[s][0]=f2b(nx[2*s].x);   af[s][1]=f2b(nx[2*s].y);
    af[s][2]=f2b(nx[2*s].z);   af[s][3]=f2b(nx[2*s].w);
    af[s][4]=f2b(nx[2*s+1].x); af[s][5]=f2b(nx[2*s+1].y);
    af[s][6]=f2b(nx[2*s+1].z); af[s][7]=f2b(nx[2*s+1].w);
  }
}

__global__ __launch_bounds__(256, 2) void mfma_gemm_k(const float* __restrict__ A,
    const unsigned short* __restrict__ WT, unsigned short* __restrict__ Cb,
    const float* __restrict__ att_src, const float* __restrict__ att_dst,
    float* __restrict__ a_src, float* __restrict__ a_dst, int M, int nTiles){
  int w   = threadIdx.x >> 6;
  int l   = threadIdx.x & 63;
  int l15 = l & 15;
  int kg  = l >> 4;
  int colbase = w*64;

  bf16x8 bfr[4][8];
  #pragma unroll
  for (int j=0;j<4;j++){
    const unsigned short* bp = WT + (size_t)(colbase + j*16 + l15)*256 + kg*8;
    #pragma unroll
    for (int ks=0;ks<8;ks++) bfr[j][ks] = *(const bf16x8*)(bp + ks*32);
  }
  float as_r[4], ad_r[4];
  #pragma unroll
  for (int j=0;j<4;j++){
    as_r[j] = att_src[colbase + j*16 + l15];
    ad_r[j] = att_dst[colbase + j*16 + l15];
  }

  int t = blockIdx.x;
  if (t >= nTiles) return;
  int row0 = t*16 + l15;
  const float* ap = A + (size_t)(row0 < M ? row0 : M-1)*256 + kg*8;
  float4 nx[8];
  load_half(nx, ap);

  while (t < nTiles){
    f32x4 acc[4];
    #pragma unroll
    for (int j=0;j<4;j++) acc[j] = (f32x4){0.f,0.f,0.f,0.f};
    bf16x8 af[4];

    cvt_half(af, nx);
    load_half(nx, ap + 128);
    #pragma unroll
    for (int s=0;s<4;s++)
      #pragma unroll
      for (int j=0;j<4;j++)
        acc[j] = __builtin_amdgcn_mfma_f32_16x16x32_bf16(af[s], bfr[j][s], acc[j], 0, 0, 0);

    int tn = t + gridDim.x;
    int rown = tn < nTiles ? tn*16 + l15 : row0;
    const float* apn = A + (size_t)(rown < M ? rown : M-1)*256 + kg*8;

    cvt_half(af, nx);
    load_half(nx, apn);
    #pragma unroll
    for (int s=0;s<4;s++)
      #pragma unroll
      for (int j=0;j<4;j++)
        acc[j] = __builtin_amdgcn_mfma_f32_16x16x32_bf16(af[s], bfr[j][4+s], acc[j], 0, 0, 0);

    int orow_base = t*16 + kg*4;
    #pragma unroll
    for (int j=0;j<4;j++)
      #pragma unroll
      for (int rr=0;rr<4;rr++){
        int orow = orow_base + rr;
        if (orow < M) Cb[(size_t)orow*256 + colbase + j*16 + l15] = (unsigned short)f2b(acc[j][rr]);
      }
    #pragma unroll
    for (int rr=0;rr<4;rr++){
      float p0s = acc[0][rr]*as_r[0] + acc[1][rr]*as_r[1];
      float p0d = acc[0][rr]*ad_r[0] + acc[1][rr]*ad_r[1];
      float p1s = acc[2][rr]*as_r[2] + acc[3][rr]*as_r[3];
      float p1d = acc[2][rr]*ad_r[2] + acc[3][rr]*ad_r[3];
      #pragma unroll
      for (int m=1;m<16;m<<=1){
        p0s += __shfl_xor(p0s,m); p0d += __shfl_xor(p0d,m);
        p1s += __shfl_xor(p1s,m); p1d += __shfl_xor(p1d,m);
      }
      int orow = orow_base + rr;
      if (l15==0 && orow < M){
        a_src[(size_t)orow*8 + 2*w]   = p0s;
        a_dst[(size_t)orow*8 + 2*w]   = p0d;
        a_src[(size_t)orow*8 + 2*w+1] = p1s;
        a_dst[(size_t)orow*8 + 2*w+1] = p1d;
      }
    }
    t = tn; row0 = rown; ap = apn;
  }
}

// -------- CSR build --------
__global__ void deg_k(const int* __restrict__ dst, int* __restrict__ deg, int E){
  int e = blockIdx.x*blockDim.x+threadIdx.x;
  if (e<E) atomicAdd(&deg[dst[e]],1);
}

__global__ __launch_bounds__(1024) void scan1_k(const int* __restrict__ deg,
                                                int* __restrict__ off,
                                                int* __restrict__ bsum, int n){
  __shared__ int wsum[16];
  int tid=threadIdx.x, lane=tid&63, wid=tid>>6;
  int i = blockIdx.x*1024 + tid;
  int v = (i<n)?deg[i]:0;
  int x = v;
  #pragma unroll
  for (int s=1;s<64;s<<=1){ int t2=__shfl_up(x,s); if (lane>=s) x+=t2; }
  if (lane==63) wsum[wid]=x;
  __syncthreads();
  if (tid<16){
    int y=wsum[tid];
    #pragma unroll
    for (int s=1;s<16;s<<=1){ int t2=__shfl_up(y,s); if (tid>=s) y+=t2; }
    wsum[tid]=y;
  }
  __syncthreads();
  int prefix=(wid? wsum[wid-1]:0);
  if (i<n) off[i]=prefix + x - v;
  if (tid==0) bsum[blockIdx.x]=wsum[15];
}

__global__ void scan2_k(int* __restrict__ bsum, int nb, int* __restrict__ offn){
  int lane = threadIdx.x;
  int v = (lane<nb)?bsum[lane]:0;
  int x = v;
  #pragma unroll
  for (int s=1;s<64;s<<=1){ int t2=__shfl_up(x,s); if (lane>=s) x+=t2; }
  if (lane<nb) bsum[lane] = x - v;
  if (lane==63) *offn = x;
}

__global__ __launch_bounds__(1024) void scan3_k(int* __restrict__ off,
                                                const int* __restrict__ bsum, int n){
  int i = blockIdx.x*1024 + threadIdx.x;
  if (i<n) off[i] += bsum[blockIdx.x];
}

__global__ void scatter_k(const int* __restrict__ src, const int* __restrict__ dst,
                          const int* __restrict__ off, int* __restrict__ cur,
                          int* __restrict__ sorted, int E){
  int e=blockIdx.x*blockDim.x+threadIdx.x;
  if (e<E){
    int d=dst[e];
    int pos=off[d]+atomicAdd(&cur[d],1);
    sorted[pos]=src[e];
  }
}

// -------- fused single-pass aggregate + softmax + LayerNorm --------
// unroll 8: all 8 row-gathers issue before the weight chain (MLP for latency)
__global__ __launch_bounds__(256) void agg2_k(const unsigned short* __restrict__ xlb,
    const float* __restrict__ a_src, const float* __restrict__ a_dst,
    const int* __restrict__ off, const int* __restrict__ sorted,
    const float* __restrict__ bias, const float* __restrict__ gamma,
    const float* __restrict__ beta, float* __restrict__ out, int n){
  int node = blockIdx.x*4 + (threadIdx.x>>6);
  int lane = threadIdx.x & 63;
  if (node >= n) return;
  int h = lane >> 3;
  float myadst = a_dst[(size_t)node*8+h];
  int s0=off[node], d=off[node+1]-s0;

  // self loop
  float wgt = __expf(lrelu(a_src[(size_t)node*8+h]+myadst));
  float den = wgt;
  ushort4 u0 = *(const ushort4*)(xlb + (size_t)node*256 + lane*4);
  float ax=wgt*b2f(u0.x), ay=wgt*b2f(u0.y), az=wgt*b2f(u0.z), aw=wgt*b2f(u0.w);

  int i=0;
  for (; i+8<=d; i+=8){
    int s[8];
    #pragma unroll
    for (int j=0;j<8;j++) s[j] = sorted[s0+i+j];
    ushort4 u[8];
    #pragma unroll
    for (int j=0;j<8;j++) u[j] = *(const ushort4*)(xlb + (size_t)s[j]*256 + lane*4);
    float wv[8];
    #pragma unroll
    for (int j=0;j<8;j++) wv[j] = __expf(lrelu(a_src[(size_t)s[j]*8+h]+myadst));
    #pragma unroll
    for (int j=0;j<8;j++){
      den += wv[j];
      ax += wv[j]*b2f(u[j].x);
      ay += wv[j]*b2f(u[j].y);
      az += wv[j]*b2f(u[j].z);
      aw += wv[j]*b2f(u[j].w);
    }
  }
  for (; i<d; i++){
    int s1 = sorted[s0+i];
    float w1 = __expf(lrelu(a_src[(size_t)s1*8+h]+myadst));
    ushort4 u1 = *(const ushort4*)(xlb + (size_t)s1*256 + lane*4);
    den += w1;
    ax += w1*b2f(u1.x); ay += w1*b2f(u1.y); az += w1*b2f(u1.z); aw += w1*b2f(u1.w);
  }

  float rd = 1.0f/den;
  float4 b4 = *(const float4*)(bias + lane*4);
  float4 o = {ax*rd+b4.x, ay*rd+b4.y, az*rd+b4.z, aw*rd+b4.w};

  float sum = o.x+o.y+o.z+o.w;
  float ssq = o.x*o.x+o.y*o.y+o.z*o.z+o.w*o.w;
  #pragma unroll
  for (int s=1;s<64;s<<=1){ sum += __shfl_xor(sum,s); ssq += __shfl_xor(ssq,s); }
  float mean = sum*(1.0f/256.0f);
  float var  = ssq*(1.0f/256.0f) - mean*mean;
  float rstd = rsqrtf(var + LNEPS);
  float4 g  = *(const float4*)(gamma + lane*4);
  float4 be = *(const float4*)(beta + lane*4);
  o.x = (o.x-mean)*rstd*g.x+be.x;
  o.y = (o.y-mean)*rstd*g.y+be.y;
  o.z = (o.z-mean)*rstd*g.z+be.z;
  o.w = (o.w-mean)*rstd*g.w+be.w;
  *(float4*)(out + (size_t)node*256 + lane*4) = o;
}

extern "C" void kernel_launch(void* const* d_in, const int* in_sizes, int n_in,
                              void* d_out, int out_size, void* d_ws, size_t ws_size,
                              hipStream_t stream){
  const float* x       = (const float*)d_in[0];
  const int*   ei      = (const int*)  d_in[1];
  const float* W       = (const float*)d_in[2];
  const float* att_src = (const float*)d_in[3];
  const float* att_dst = (const float*)d_in[4];
  const float* bias    = (const float*)d_in[5];
  const float* gamma   = (const float*)d_in[6];
  const float* beta    = (const float*)d_in[7];
  float* out = (float*)d_out;

  int N = in_sizes[0]/256;
  int E = in_sizes[1]/2;
  const int* srcp = ei;
  const int* dstp = ei + E;

  unsigned short* xlb = (unsigned short*)d_ws;               // N*256 bf16
  float* a_src = (float*)(xlb + (size_t)N*256);
  float* a_dst = a_src + (size_t)N*8;
  int*   deg   = (int*)(a_dst + (size_t)N*8);
  int*   off   = deg + N;
  int*   cur   = off + N + 1;
  int*   sorted= cur + N;
  int*   bsum  = sorted + E;
  unsigned short* WT = (unsigned short*)(bsum + 1024);

  hipMemsetAsync(deg, 0, (size_t)N*sizeof(int), stream);
  hipMemsetAsync(cur, 0, (size_t)N*sizeof(int), stream);

  int nb = (N + 1023)/1024;
  int nTiles = (N + 15)/16;

  wt_k<<<256, 256, 0, stream>>>(W, WT);
  mfma_gemm_k<<<512, 256, 0, stream>>>(x, WT, xlb, att_src, att_dst, a_src, a_dst, N, nTiles);
  deg_k<<<(E+255)/256, 256, 0, stream>>>(dstp, deg, E);
  scan1_k<<<nb, 1024, 0, stream>>>(deg, off, bsum, N);
  scan2_k<<<1, 64, 0, stream>>>(bsum, nb, off + N);
  scan3_k<<<nb, 1024, 0, stream>>>(off, bsum, N);
  scatter_k<<<(E+255)/256, 256, 0, stream>>>(srcp, dstp, off, cur, sorted, E);
  agg2_k<<<(N+3)/4, 256, 0, stream>>>(xlb, a_src, a_dst, off, sorted, bias, gamma, beta, out, N);
}

// Round 6
// 209.698 us; speedup vs baseline: 1.0441x; 1.0441x over previous
//
#include <hip/hip_runtime.h>
#include <math.h>

#define NEG 0.2f
#define LNEPS 1e-5f

typedef __attribute__((ext_vector_type(8))) short bf16x8;
typedef __attribute__((ext_vector_type(8))) unsigned short u16x8;
typedef __attribute__((ext_vector_type(4))) float f32x4;

__device__ __forceinline__ float lrelu(float x){ return x > 0.f ? x : NEG*x; }

// f32 -> bf16 (round to nearest even), as raw short
__device__ __forceinline__ short f2b(float f){
  unsigned u = __float_as_uint(f);
  unsigned r = u + 0x7fffu + ((u >> 16) & 1u);
  return (short)(r >> 16);
}
__device__ __forceinline__ float b2f(unsigned short u){
  return __uint_as_float(((unsigned)u) << 16);
}

// -------- W transpose + bf16 convert: WT[c][k] = bf16(W[k][c]) --------
__global__ __launch_bounds__(256) void wt_k(const float* __restrict__ W,
                                            unsigned short* __restrict__ WT){
  int idx = blockIdx.x*256 + threadIdx.x;   // 65536 elements
  int k = idx >> 8, c = idx & 255;
  WT[c*256 + k] = (unsigned short)f2b(W[idx]);
}

// -------- MFMA GEMM + fused att half-logits, B-in-registers --------
__device__ __forceinline__ void load_half(float4 nx[8], const float* p){
  #pragma unroll
  for (int s=0;s<4;s++){
    nx[2*s]   = *(const float4*)(p + s*32);
    nx[2*s+1] = *(const float4*)(p + s*32 + 4);
  }
}
__device__ __forceinline__ void cvt_half(bf16x8 af[4], const float4 nx[8]){
  #pragma unroll
  for (int s=0;s<4;s++){
    af[s][0]=f2b(nx[2*s].x);   af[s][1]=f2b(nx[2*s].y);
    af[s][2]=f2b(nx[2*s].z);   af[s][3]=f2b(nx[2*s].w);
    af[s][4]=f2b(nx[2*s+1].x); af[s][5]=f2b(nx[2*s+1].y);
    af[s][6]=f2b(nx[2*s+1].z); af[s][7]=f2b(nx[2*s+1].w);
  }
}

__global__ __launch_bounds__(256, 2) void mfma_gemm_k(const float* __restrict__ A,
    const unsigned short* __restrict__ WT, unsigned short* __restrict__ Cb,
    const float* __restrict__ att_src, const float* __restrict__ att_dst,
    float* __restrict__ a_src, float* __restrict__ a_dst, int M, int nTiles){
  int w   = threadIdx.x >> 6;
  int l   = threadIdx.x & 63;
  int l15 = l & 15;
  int kg  = l >> 4;
  int colbase = w*64;

  bf16x8 bfr[4][8];
  #pragma unroll
  for (int j=0;j<4;j++){
    const unsigned short* bp = WT + (size_t)(colbase + j*16 + l15)*256 + kg*8;
    #pragma unroll
    for (int ks=0;ks<8;ks++) bfr[j][ks] = *(const bf16x8*)(bp + ks*32);
  }
  float as_r[4], ad_r[4];
  #pragma unroll
  for (int j=0;j<4;j++){
    as_r[j] = att_src[colbase + j*16 + l15];
    ad_r[j] = att_dst[colbase + j*16 + l15];
  }

  int t = blockIdx.x;
  if (t >= nTiles) return;
  int row0 = t*16 + l15;
  const float* ap = A + (size_t)(row0 < M ? row0 : M-1)*256 + kg*8;
  float4 nx[8];
  load_half(nx, ap);

  while (t < nTiles){
    f32x4 acc[4];
    #pragma unroll
    for (int j=0;j<4;j++) acc[j] = (f32x4){0.f,0.f,0.f,0.f};
    bf16x8 af[4];

    cvt_half(af, nx);
    load_half(nx, ap + 128);
    #pragma unroll
    for (int s=0;s<4;s++)
      #pragma unroll
      for (int j=0;j<4;j++)
        acc[j] = __builtin_amdgcn_mfma_f32_16x16x32_bf16(af[s], bfr[j][s], acc[j], 0, 0, 0);

    int tn = t + gridDim.x;
    int rown = tn < nTiles ? tn*16 + l15 : row0;
    const float* apn = A + (size_t)(rown < M ? rown : M-1)*256 + kg*8;

    cvt_half(af, nx);
    load_half(nx, apn);
    #pragma unroll
    for (int s=0;s<4;s++)
      #pragma unroll
      for (int j=0;j<4;j++)
        acc[j] = __builtin_amdgcn_mfma_f32_16x16x32_bf16(af[s], bfr[j][4+s], acc[j], 0, 0, 0);

    int orow_base = t*16 + kg*4;
    #pragma unroll
    for (int j=0;j<4;j++)
      #pragma unroll
      for (int rr=0;rr<4;rr++){
        int orow = orow_base + rr;
        if (orow < M) Cb[(size_t)orow*256 + colbase + j*16 + l15] = (unsigned short)f2b(acc[j][rr]);
      }
    #pragma unroll
    for (int rr=0;rr<4;rr++){
      float p0s = acc[0][rr]*as_r[0] + acc[1][rr]*as_r[1];
      float p0d = acc[0][rr]*ad_r[0] + acc[1][rr]*ad_r[1];
      float p1s = acc[2][rr]*as_r[2] + acc[3][rr]*as_r[3];
      float p1d = acc[2][rr]*ad_r[2] + acc[3][rr]*ad_r[3];
      #pragma unroll
      for (int m=1;m<16;m<<=1){
        p0s += __shfl_xor(p0s,m); p0d += __shfl_xor(p0d,m);
        p1s += __shfl_xor(p1s,m); p1d += __shfl_xor(p1d,m);
      }
      int orow = orow_base + rr;
      if (l15==0 && orow < M){
        a_src[(size_t)orow*8 + 2*w]   = p0s;
        a_dst[(size_t)orow*8 + 2*w]   = p0d;
        a_src[(size_t)orow*8 + 2*w+1] = p1s;
        a_dst[(size_t)orow*8 + 2*w+1] = p1d;
      }
    }
    t = tn; row0 = rown; ap = apn;
  }
}

// -------- CSR build (self-loops folded in: deg starts at 1) --------
__global__ void dinit_k(int* __restrict__ deg, int n){
  int i = blockIdx.x*blockDim.x+threadIdx.x;
  if (i<n) deg[i]=1;
}

__global__ void deg_k(const int* __restrict__ dst, int* __restrict__ deg, int E){
  int e = blockIdx.x*blockDim.x+threadIdx.x;
  if (e<E) atomicAdd(&deg[dst[e]],1);
}

__global__ __launch_bounds__(1024) void scan1_k(const int* __restrict__ deg,
                                                int* __restrict__ off,
                                                int* __restrict__ bsum, int n){
  __shared__ int wsum[16];
  int tid=threadIdx.x, lane=tid&63, wid=tid>>6;
  int i = blockIdx.x*1024 + tid;
  int v = (i<n)?deg[i]:0;
  int x = v;
  #pragma unroll
  for (int s=1;s<64;s<<=1){ int t2=__shfl_up(x,s); if (lane>=s) x+=t2; }
  if (lane==63) wsum[wid]=x;
  __syncthreads();
  if (tid<16){
    int y=wsum[tid];
    #pragma unroll
    for (int s=1;s<16;s<<=1){ int t2=__shfl_up(y,s); if (tid>=s) y+=t2; }
    wsum[tid]=y;
  }
  __syncthreads();
  int prefix=(wid? wsum[wid-1]:0);
  if (i<n) off[i]=prefix + x - v;
  if (tid==0) bsum[blockIdx.x]=wsum[15];
}

__global__ void scan2_k(int* __restrict__ bsum, int nb, int* __restrict__ offn){
  int lane = threadIdx.x;
  int v = (lane<nb)?bsum[lane]:0;
  int x = v;
  #pragma unroll
  for (int s=1;s<64;s<<=1){ int t2=__shfl_up(x,s); if (lane>=s) x+=t2; }
  if (lane<nb) bsum[lane] = x - v;
  if (lane==63) *offn = x;
}

__global__ __launch_bounds__(1024) void scan3_k(int* __restrict__ off,
                                                const int* __restrict__ bsum, int n){
  int i = blockIdx.x*1024 + threadIdx.x;
  if (i<n) off[i] += bsum[blockIdx.x];
}

// plant self edge at slot 0 of each segment; cur starts at 1
__global__ void self_k(const int* __restrict__ off, int* __restrict__ sorted,
                       int* __restrict__ cur, int n){
  int i = blockIdx.x*blockDim.x+threadIdx.x;
  if (i<n){ sorted[off[i]] = i; cur[i] = 1; }
}

__global__ void scatter_k(const int* __restrict__ src, const int* __restrict__ dst,
                          const int* __restrict__ off, int* __restrict__ cur,
                          int* __restrict__ sorted, int E){
  int e=blockIdx.x*blockDim.x+threadIdx.x;
  if (e<E){
    int d=dst[e];
    int pos=off[d]+atomicAdd(&cur[d],1);
    sorted[pos]=src[e];
  }
}

// -------- fused aggregate + softmax + LayerNorm, 2 edges/instruction --------
// Wave = 1 node. Lanes split in two 32-lane halves; each half gathers a full
// 512B row at 16B/lane. Cross-half shfl_xor(32) merges acc+den at the end.
__global__ __launch_bounds__(256) void agg3_k(const unsigned short* __restrict__ xlb,
    const float* __restrict__ a_src, const float* __restrict__ a_dst,
    const int* __restrict__ off, const int* __restrict__ sorted,
    const float* __restrict__ bias, const float* __restrict__ gamma,
    const float* __restrict__ beta, float* __restrict__ out, int n){
  int node = blockIdx.x*4 + (threadIdx.x>>6);
  if (node >= n) return;
  int lane = threadIdx.x & 63;
  int half = lane >> 5;
  int sl   = lane & 31;
  int h    = sl >> 2;          // 4 lanes per head
  float adst = a_dst[(size_t)node*8 + h];
  int s0 = off[node], dd = off[node+1] - s0;   // includes self edge

  float acc[8] = {0.f,0.f,0.f,0.f,0.f,0.f,0.f,0.f};
  float den = 0.f;

  int i = 0;
  for (; i+8 <= dd; i += 8){
    int s[4];
    #pragma unroll
    for (int j=0;j<4;j++) s[j] = sorted[s0 + i + 2*j + half];
    u16x8 u[4];
    #pragma unroll
    for (int j=0;j<4;j++) u[j] = *(const u16x8*)(xlb + (size_t)s[j]*256 + sl*8);
    float wv[4];
    #pragma unroll
    for (int j=0;j<4;j++) wv[j] = __expf(lrelu(a_src[(size_t)s[j]*8+h]+adst));
    #pragma unroll
    for (int j=0;j<4;j++){
      den += wv[j];
      #pragma unroll
      for (int k=0;k<8;k++) acc[k] += wv[j]*b2f((unsigned short)u[j][k]);
    }
  }
  for (; i < dd; i += 2){
    int idx = i + half;
    bool ok = idx < dd;
    int s1 = ok ? sorted[s0+idx] : node;
    u16x8 u1 = *(const u16x8*)(xlb + (size_t)s1*256 + sl*8);
    float w1 = ok ? __expf(lrelu(a_src[(size_t)s1*8+h]+adst)) : 0.f;
    den += w1;
    #pragma unroll
    for (int k=0;k<8;k++) acc[k] += w1*b2f((unsigned short)u1[k]);
  }

  // cross-half merge
  den += __shfl_xor(den, 32);
  #pragma unroll
  for (int k=0;k<8;k++) acc[k] += __shfl_xor(acc[k], 32);

  float rd = 1.0f/den;
  float4 bia0 = *(const float4*)(bias + sl*8);
  float4 bia1 = *(const float4*)(bias + sl*8 + 4);
  float o[8];
  o[0]=acc[0]*rd+bia0.x; o[1]=acc[1]*rd+bia0.y; o[2]=acc[2]*rd+bia0.z; o[3]=acc[3]*rd+bia0.w;
  o[4]=acc[4]*rd+bia1.x; o[5]=acc[5]*rd+bia1.y; o[6]=acc[6]*rd+bia1.z; o[7]=acc[7]*rd+bia1.w;

  float sum=0.f, ssq=0.f;
  #pragma unroll
  for (int k=0;k<8;k++){ sum += o[k]; ssq += o[k]*o[k]; }
  #pragma unroll
  for (int s=1;s<32;s<<=1){ sum += __shfl_xor(sum,s); ssq += __shfl_xor(ssq,s); }
  float mean = sum*(1.0f/256.0f);
  float var  = ssq*(1.0f/256.0f) - mean*mean;
  float rstd = rsqrtf(var + LNEPS);

  // each lane writes 4 features: f = sl*8 + half*4
  int f = sl*8 + half*4;
  float4 g  = *(const float4*)(gamma + f);
  float4 be = *(const float4*)(beta + f);
  int kb = half*4;
  float4 ov;
  ov.x = (o[kb+0]-mean)*rstd*g.x+be.x;
  ov.y = (o[kb+1]-mean)*rstd*g.y+be.y;
  ov.z = (o[kb+2]-mean)*rstd*g.z+be.z;
  ov.w = (o[kb+3]-mean)*rstd*g.w+be.w;
  *(float4*)(out + (size_t)node*256 + f) = ov;
}

extern "C" void kernel_launch(void* const* d_in, const int* in_sizes, int n_in,
                              void* d_out, int out_size, void* d_ws, size_t ws_size,
                              hipStream_t stream){
  const float* x       = (const float*)d_in[0];
  const int*   ei      = (const int*)  d_in[1];
  const float* W       = (const float*)d_in[2];
  const float* att_src = (const float*)d_in[3];
  const float* att_dst = (const float*)d_in[4];
  const float* bias    = (const float*)d_in[5];
  const float* gamma   = (const float*)d_in[6];
  const float* beta    = (const float*)d_in[7];
  float* out = (float*)d_out;

  int N = in_sizes[0]/256;
  int E = in_sizes[1]/2;
  const int* srcp = ei;
  const int* dstp = ei + E;

  unsigned short* xlb = (unsigned short*)d_ws;               // N*256 bf16
  float* a_src = (float*)(xlb + (size_t)N*256);
  float* a_dst = a_src + (size_t)N*8;
  int*   deg   = (int*)(a_dst + (size_t)N*8);
  int*   off   = deg + N;
  int*   cur   = off + N + 1;
  int*   sorted= cur + N;                                    // E+N entries
  int*   bsum  = sorted + E + N;
  unsigned short* WT = (unsigned short*)(bsum + 1024);

  int nb = (N + 1023)/1024;
  int nTiles = (N + 15)/16;

  wt_k<<<256, 256, 0, stream>>>(W, WT);
  mfma_gemm_k<<<512, 256, 0, stream>>>(x, WT, xlb, att_src, att_dst, a_src, a_dst, N, nTiles);
  dinit_k<<<(N+255)/256, 256, 0, stream>>>(deg, N);
  deg_k<<<(E+255)/256, 256, 0, stream>>>(dstp, deg, E);
  scan1_k<<<nb, 1024, 0, stream>>>(deg, off, bsum, N);
  scan2_k<<<1, 64, 0, stream>>>(bsum, nb, off + N);
  scan3_k<<<nb, 1024, 0, stream>>>(off, bsum, N);
  self_k<<<(N+255)/256, 256, 0, stream>>>(off, sorted, cur, N);
  scatter_k<<<(E+255)/256, 256, 0, stream>>>(srcp, dstp, off, cur, sorted, E);
  agg3_k<<<(N+3)/4, 256, 0, stream>>>(xlb, a_src, a_dst, off, sorted, bias, gamma, beta, out, N);
}